// Round 1
// baseline (10720.344 us; speedup 1.0000x reference)
//
#include <hip/hip_runtime.h>

#define Tn 512
#define Bn 64
#define In 300
#define Hn 1000
#define G4H 4000
#define KP 1024   // padded K for recurrence (H=1000 -> 1024)
#define KI 320    // padded K for input GEMM (I=300 -> 320)
#define NB 250    // scan blocks: 250 * 4 jh-cols = 1000

typedef __attribute__((ext_vector_type(8))) short bf16x8;
typedef __attribute__((ext_vector_type(4))) float f32x4;
typedef unsigned int u32;
typedef unsigned short u16;

__device__ __forceinline__ u16 f2bf(float x) {
  union { float f; u32 u; } v; v.f = x;
  u32 r = (v.u + 0x7fffu + ((v.u >> 16) & 1u)) >> 16;
  return (u16)r;
}
__device__ __forceinline__ float bf2f(u16 s) {
  union { u32 u; float f; } v; v.u = ((u32)s) << 16;
  return v.f;
}
__device__ __forceinline__ float sigm(float x) { return 1.f / (1.f + __expf(-x)); }
__device__ __forceinline__ float tanh_f(float x) {
  float e = __expf(2.f * x);
  return 1.f - 2.f / (e + 1.f);
}

// ---------------------------------------------------------------- converts
__global__ void conv_pad(const float* __restrict__ src, u16* __restrict__ dst,
                         int rows, int scols, int dcols) {
  int idx = blockIdx.x * 256 + threadIdx.x;
  int total = rows * dcols;
  if (idx >= total) return;
  int r = idx / dcols, k = idx - r * dcols;
  float v = (k < scols) ? src[(size_t)r * scols + k] : 0.f;
  dst[idx] = f2bf(v);
}

// init h double-buffer (bf16, K-padded with zeros) + zero the barrier area
__global__ void init_scan(const float* __restrict__ h0, u16* __restrict__ hbuf,
                          u32* __restrict__ bar) {
  int idx = blockIdx.x * 256 + threadIdx.x;
  if (idx < 1024) bar[idx] = 0;
  if (idx >= 2 * Bn * KP) return;
  int which = idx >> 16;          // 64*1024 = 65536 per buffer
  int rem = idx & 65535;
  int b = rem >> 10, k = rem & (KP - 1);
  float v = (which == 0 && k < Hn) ? h0[b * Hn + k] : 0.f;
  hbuf[idx] = f2bf(v);
}

// ---------------------------------------------------------------- xg GEMM
// C[m, n] = inputs_bf16[m, :] . W_ih_bf16[n, :] + b_ih[n] + b_hh[n]
// m = t*64 + b (32768), n = gate column (4000). Natural layout [m][4000].
template<bool XF32>
__global__ void __launch_bounds__(256)
gemm_xg(const u16* __restrict__ A, const u16* __restrict__ Wb,
        const float* __restrict__ b_ih, const float* __restrict__ b_hh,
        void* __restrict__ xg_out) {
  const int lane = threadIdx.x & 63, w = threadIdx.x >> 6;
  const int m0 = blockIdx.x * 64, n0 = blockIdx.y * 64;
  f32x4 acc[4] = {};
  const int arow = m0 + w * 16 + (lane & 15);
  const int koff = (lane >> 4) * 8;
  int nrow[4];
#pragma unroll
  for (int nt = 0; nt < 4; ++nt) {
    int n = n0 + nt * 16 + (lane & 15);
    nrow[nt] = (n < G4H) ? n : (G4H - 1);
  }
  for (int kc = 0; kc < KI / 32; ++kc) {
    bf16x8 a = *(const bf16x8*)(A + (size_t)arow * KI + kc * 32 + koff);
#pragma unroll
    for (int nt = 0; nt < 4; ++nt) {
      bf16x8 bb = *(const bf16x8*)(Wb + (size_t)nrow[nt] * KI + kc * 32 + koff);
      acc[nt] = __builtin_amdgcn_mfma_f32_16x16x32_bf16(a, bb, acc[nt], 0, 0, 0);
    }
  }
#pragma unroll
  for (int nt = 0; nt < 4; ++nt) {
    int col = n0 + nt * 16 + (lane & 15);
    if (col >= G4H) continue;
    float bias = b_ih[col] + b_hh[col];
    int mrow = m0 + w * 16 + (lane >> 4) * 4;
#pragma unroll
    for (int r = 0; r < 4; ++r) {
      float v = acc[nt][r] + bias;
      size_t o = (size_t)(mrow + r) * G4H + col;
      if constexpr (XF32) ((float*)xg_out)[o] = v;
      else                ((u16*)xg_out)[o] = f2bf(v);
    }
  }
}

// ---------------------------------------------------------------- barrier
// two-level grid barrier: 16 groups of <=16 blocks; 64B-spaced counters.
// bar[0]=root count, bar[16]=generation, bar[32 + g*16]=group count.
__device__ __forceinline__ void grid_sync(u32* bar, u32 target) {
  __syncthreads();
  if (threadIdx.x == 0) {
    const int nb = (int)gridDim.x;
    const int g = (int)blockIdx.x >> 4;
    const int gsz0 = nb - (g << 4);
    const int gsz = gsz0 < 16 ? gsz0 : 16;
    u32* gcnt = bar + 32 + g * 16;
    u32* root = bar;
    u32* gen = bar + 16;
    u32 a = __hip_atomic_fetch_add(gcnt, 1u, __ATOMIC_ACQ_REL, __HIP_MEMORY_SCOPE_AGENT);
    if (a == (u32)(gsz - 1)) {
      __hip_atomic_store(gcnt, 0u, __ATOMIC_RELAXED, __HIP_MEMORY_SCOPE_AGENT);
      u32 G = (u32)((nb + 15) >> 4);
      u32 r = __hip_atomic_fetch_add(root, 1u, __ATOMIC_ACQ_REL, __HIP_MEMORY_SCOPE_AGENT);
      if (r == G - 1) {
        __hip_atomic_store(root, 0u, __ATOMIC_RELAXED, __HIP_MEMORY_SCOPE_AGENT);
        __hip_atomic_store(gen, target, __ATOMIC_RELEASE, __HIP_MEMORY_SCOPE_AGENT);
      }
    }
    while (__hip_atomic_load(gen, __ATOMIC_RELAXED, __HIP_MEMORY_SCOPE_AGENT) < target) {
      __builtin_amdgcn_s_sleep(2);
    }
    (void)__hip_atomic_load(gen, __ATOMIC_ACQUIRE, __HIP_MEMORY_SCOPE_AGENT);
  }
  __syncthreads();
}

// ---------------------------------------------------------------- scan
// Persistent kernel. Block nb owns hidden cols [nb*4, nb*4+4): W_hh rows
// {g*1000 + nb*4 + jl} stay bf16 in LDS (swizzled) for all 512 steps.
// Per step: gates[64 x 16] = h[64 x 1024] . Wl^T, via 16x16x32 MFMA
// (wave w handles batch rows 16w..16w+15), then pointwise with c held
// in a register per thread (thread <-> (b = tid>>2, jl = tid&3)).
template<bool XF32>
__global__ void __launch_bounds__(256)
lstm_scan(const float* __restrict__ Whh, const float* __restrict__ c0,
          const void* __restrict__ xg_, u16* __restrict__ hbuf,
          float* __restrict__ out, u32* __restrict__ bar) {
  __shared__ __align__(16) u16 Wl[16 * KP];
  __shared__ float Sc[4][16][17];
  const int tid = threadIdx.x;
  const int lane = tid & 63;
  const int w = tid >> 6;
  const int nb = blockIdx.x;

  // stage W_hh slice -> LDS bf16, row r = gate*4 + jl, col swizzle +8*r
  for (int idx = tid; idx < 16 * KP; idx += 256) {
    int r = idx >> 10;
    int k = idx & (KP - 1);
    int g = r >> 2, jl = r & 3;
    float v = (k < Hn) ? Whh[(size_t)(g * Hn + nb * 4 + jl) * Hn + k] : 0.f;
    Wl[(r << 10) + ((k + 8 * r) & (KP - 1))] = f2bf(v);
  }
  const int b = tid >> 2;
  const int jl = tid & 3;
  const int jh = nb * 4 + jl;
  float c = c0[b * Hn + jh];
  __syncthreads();

  const int arow = w * 16 + (lane & 15);
  const int brow = lane & 15;
  const int koff = (lane >> 4) * 8;
  const float* xf = (const float*)xg_;
  const u16* xh = (const u16*)xg_;

  for (int t = 0; t < Tn; ++t) {
    const u16* hc = hbuf + (size_t)(t & 1) * Bn * KP;
    u16* hn = hbuf + (size_t)((t + 1) & 1) * Bn * KP;

    // prefetch this thread's 4 gate inputs (independent of the K loop)
    size_t xbase = ((size_t)t * Bn + b) * G4H + jh;
    float x0, x1, x2, x3;
    if constexpr (XF32) {
      x0 = xf[xbase]; x1 = xf[xbase + Hn];
      x2 = xf[xbase + 2 * Hn]; x3 = xf[xbase + 3 * Hn];
    } else {
      x0 = bf2f(xh[xbase]); x1 = bf2f(xh[xbase + Hn]);
      x2 = bf2f(xh[xbase + 2 * Hn]); x3 = bf2f(xh[xbase + 3 * Hn]);
    }

    f32x4 acc = {0.f, 0.f, 0.f, 0.f};
#pragma unroll 8
    for (int kc = 0; kc < KP / 32; ++kc) {
      const int kk = kc * 32 + koff;
      bf16x8 av = *(const bf16x8*)(hc + (size_t)arow * KP + kk);
      bf16x8 bv = *(const bf16x8*)(&Wl[(brow << 10) + ((kk + 8 * brow) & (KP - 1))]);
      acc = __builtin_amdgcn_mfma_f32_16x16x32_bf16(av, bv, acc, 0, 0, 0);
    }

    // redistribute C tile within the wave via LDS (writer wave == reader wave)
#pragma unroll
    for (int r = 0; r < 4; ++r)
      Sc[w][(lane >> 4) * 4 + r][lane & 15] = acc[r];

    float gi = Sc[w][b & 15][jl] + x0;
    float gf = Sc[w][b & 15][4 + jl] + x1;
    float gg = Sc[w][b & 15][8 + jl] + x2;
    float go = Sc[w][b & 15][12 + jl] + x3;
    float iv = sigm(gi), fv = sigm(gf), gv = tanh_f(gg), ov = sigm(go);
    c = fv * c + iv * gv;
    float h = ov * tanh_f(c);
    out[((size_t)t * Bn + b) * Hn + jh] = h;
    hn[b * KP + jh] = f2bf(h);

    grid_sync(bar, (u32)(t + 1));
  }
}

// ---------------------------------------------------------------- launch
extern "C" void kernel_launch(void* const* d_in, const int* in_sizes, int n_in,
                              void* d_out, int out_size, void* d_ws, size_t ws_size,
                              hipStream_t stream) {
  const float* inputs = (const float*)d_in[0];
  const float* h0 = (const float*)d_in[1];
  const float* c0 = (const float*)d_in[2];
  const float* W_ih = (const float*)d_in[3];
  const float* W_hh = (const float*)d_in[4];
  const float* b_ih = (const float*)d_in[5];
  const float* b_hh = (const float*)d_in[6];
  float* out = (float*)d_out;

  char* ws = (char*)d_ws;
  size_t off = 0;
  auto carve = [&](size_t bytes) {
    char* p = ws + off;
    off = (off + bytes + 255) & ~(size_t)255;
    return p;
  };
  u32* bar = (u32*)carve(4096);
  u16* in_bf = (u16*)carve((size_t)Tn * Bn * KI * 2);
  u16* wih_bf = (u16*)carve((size_t)G4H * KI * 2);
  u16* hbuf = (u16*)carve((size_t)2 * Bn * KP * 2);
  size_t fixed = off;
  size_t xg_f32 = (size_t)Tn * Bn * G4H * 4;
  bool xf32 = (ws_size >= fixed + xg_f32);
  void* xg = (void*)carve(xf32 ? xg_f32 : xg_f32 / 2);

  int tot_in = Tn * Bn * KI;
  conv_pad<<<dim3((tot_in + 255) / 256), dim3(256), 0, stream>>>(
      inputs, in_bf, Tn * Bn, In, KI);
  int tot_w = G4H * KI;
  conv_pad<<<dim3((tot_w + 255) / 256), dim3(256), 0, stream>>>(
      W_ih, wih_bf, G4H, In, KI);
  init_scan<<<dim3(512), dim3(256), 0, stream>>>(h0, hbuf, bar);

  if (xf32) {
    gemm_xg<true><<<dim3(Tn * Bn / 64, (G4H + 63) / 64), dim3(256), 0, stream>>>(
        in_bf, wih_bf, b_ih, b_hh, xg);
    lstm_scan<true><<<dim3(NB), dim3(256), 0, stream>>>(
        W_hh, c0, xg, hbuf, out, bar);
  } else {
    gemm_xg<false><<<dim3(Tn * Bn / 64, (G4H + 63) / 64), dim3(256), 0, stream>>>(
        in_bf, wih_bf, b_ih, b_hh, xg);
    lstm_scan<false><<<dim3(NB), dim3(256), 0, stream>>>(
        W_hh, c0, xg, hbuf, out, bar);
  }
}